// Round 3
// baseline (146.210 us; speedup 1.0000x reference)
//
#include <hip/hip_runtime.h>
#include <hip/hip_bf16.h>
#include <math.h>

#define NHEADS 8
#define NTOK   1024
#define MTOK   2048

typedef __attribute__((ext_vector_type(8))) short  sh8;
typedef __attribute__((ext_vector_type(8))) __bf16 bf16x8;
typedef __attribute__((ext_vector_type(4))) float  f32x4;

__device__ __forceinline__ short f2bf(float v) {
    return __builtin_bit_cast(short, __float2bfloat16(v));
}
__device__ __forceinline__ f32x4 mfma16(sh8 a, sh8 b, f32x4 c) {
    return __builtin_amdgcn_mfma_f32_16x16x32_bf16(
        __builtin_bit_cast(bf16x8, a), __builtin_bit_cast(bf16x8, b), c, 0, 0, 0);
}
__device__ __forceinline__ void aload16(void* lds, const void* g) {
    __builtin_amdgcn_global_load_lds(
        (const __attribute__((address_space(1))) unsigned int*)g,
        (__attribute__((address_space(3))) unsigned int*)lds, 16, 0, 0);
}

// ---------------- LayerNorm -> bf16 ----------------
__global__ __launch_bounds__(256) void ln_bf16(const float* __restrict__ x,
    const float* __restrict__ g, const float* __restrict__ bta, short* __restrict__ y)
{
    int row = blockIdx.x, t = threadIdx.x;
    const float* xr = x + (size_t)row * 512;
    float2 v = *reinterpret_cast<const float2*>(&xr[t*2]);
    float s = v.x + v.y, ss = v.x*v.x + v.y*v.y;
    #pragma unroll
    for (int m = 1; m < 64; m <<= 1) { s += __shfl_xor(s, m); ss += __shfl_xor(ss, m); }
    __shared__ float red[8];
    int wid = t >> 6, lane = t & 63;
    if (!lane) { red[wid] = s; red[4+wid] = ss; }
    __syncthreads();
    s = red[0]+red[1]+red[2]+red[3]; ss = red[4]+red[5]+red[6]+red[7];
    float mu = s*(1.f/512), var = ss*(1.f/512) - mu*mu, rs = rsqrtf(var + 1e-5f);
    float2 gg = *reinterpret_cast<const float2*>(&g[t*2]);
    float2 bb = *reinterpret_cast<const float2*>(&bta[t*2]);
    short2 o; o.x = f2bf((v.x-mu)*rs*gg.x + bb.x); o.y = f2bf((v.y-mu)*rs*gg.y + bb.y);
    *reinterpret_cast<short2*>(&y[(size_t)row*512 + t*2]) = o;
}

// ---------------- fp32 W[K][N] -> bf16 W^T[N][K] ----------------
__global__ __launch_bounds__(256) void wconv_t(const float* __restrict__ W,
    short* __restrict__ WT, int K, int N)
{
    __shared__ float t[32][33];
    int bn = blockIdx.x * 32, bk = blockIdx.y * 32;
    int c = threadIdx.x & 31, r8 = threadIdx.x >> 5;
    #pragma unroll
    for (int i = 0; i < 4; ++i) {
        int r = r8 + i*8;
        t[r][c] = W[(size_t)(bk + r)*N + bn + c];
    }
    __syncthreads();
    #pragma unroll
    for (int i = 0; i < 4; ++i) {
        int r = r8 + i*8;
        WT[(size_t)(bn + r)*K + bk + c] = f2bf(t[c][r]);
    }
}

// ---------------- o[i] = a[i] + bias[i % 512]  (f32, vectorized) ----------------
__global__ __launch_bounds__(256) void addbias_f32(const float* __restrict__ a,
    const float* __restrict__ bias, float* __restrict__ o)
{
    int e = (blockIdx.x*256 + threadIdx.x)*4;
    float4 av = *reinterpret_cast<const float4*>(a + e);
    float4 bv = *reinterpret_cast<const float4*>(bias + (e & 511));
    float4 ov = {av.x+bv.x, av.y+bv.y, av.z+bv.z, av.w+bv.w};
    *reinterpret_cast<float4*>(o + e) = ov;
}

// ---------------- bf16 MFMA GEMM, 64x64 tile, BK=64, 2-phase dbuf --------------
// C[M][N] = A[M][K] @ BT[N][K]^T
// EPI: 0 = bias, bf16/f32 out; 2 = bias+gelu; 3 = split-K atomicAdd into f32 out
template<int EPI, bool OUTBF, bool BIAS_ROW, int SPLITK>
__global__ __launch_bounds__(256) void gemm64(
    const short* __restrict__ A, const short* __restrict__ BT,
    const float* __restrict__ bias, void* __restrict__ Cout,
    int M, int N, int K, int nbx)
{
    __shared__ sh8 As8[2][512];
    __shared__ sh8 Bs8[2][512];
    int tid = threadIdx.x;
    int w = tid >> 6, lane = tid & 63, lr = lane & 15, lg = lane >> 4;
    int wr = w >> 1, wc = w & 1;
    // bijective XCD swizzle (gridDim.x % 8 == 0 for all launches)
    int cpx = gridDim.x >> 3;
    int swz = (blockIdx.x & 7)*cpx + (blockIdx.x >> 3);
    int bx = swz % nbx, by = swz / nbx;
    int bm0 = by*64, bn0 = bx*64;
    int kbeg = (K / SPLITK) * blockIdx.z;
    int nt = (K / SPLITK) / 64;

    f32x4 zero = {0.f,0.f,0.f,0.f};
    f32x4 acc[2][2];
    #pragma unroll
    for (int m = 0; m < 2; ++m)
        #pragma unroll
        for (int n = 0; n < 2; ++n) acc[m][n] = zero;

    #define STAGE(buf, k0) { \
        _Pragma("unroll") \
        for (int it = 0; it < 2; ++it) { \
            int s = tid + it*256; \
            int r = s >> 3, g = s & 7; \
            int ksw = (k0) + ((g ^ (r & 7)) << 3); \
            aload16(&As8[buf][s], A  + (size_t)(bm0 + r)*K + ksw); \
            aload16(&Bs8[buf][s], BT + (size_t)(bn0 + r)*K + ksw); \
        } }

    STAGE(0, kbeg)
    asm volatile("s_waitcnt vmcnt(0)" ::: "memory");
    __syncthreads();

    for (int t = 0; t < nt; ++t) {
        int buf = t & 1;
        if (t + 1 < nt) STAGE(buf ^ 1, kbeg + (t+1)*64)
        sh8 af[2][2], bfv[2][2];
        #pragma unroll
        for (int m = 0; m < 2; ++m) {
            int R = wr*32 + m*16 + lr;
            #pragma unroll
            for (int s = 0; s < 2; ++s) af[m][s] = As8[buf][R*8 + ((s*4+lg) ^ (R & 7))];
        }
        #pragma unroll
        for (int n = 0; n < 2; ++n) {
            int R = wc*32 + n*16 + lr;
            #pragma unroll
            for (int s = 0; s < 2; ++s) bfv[n][s] = Bs8[buf][R*8 + ((s*4+lg) ^ (R & 7))];
        }
        #pragma unroll
        for (int m = 0; m < 2; ++m)
            #pragma unroll
            for (int n = 0; n < 2; ++n)
                #pragma unroll
                for (int s = 0; s < 2; ++s)
                    acc[m][n] = mfma16(af[m][s], bfv[n][s], acc[m][n]);
        asm volatile("s_waitcnt vmcnt(0)" ::: "memory");
        __syncthreads();
    }
    #undef STAGE

    #pragma unroll
    for (int m = 0; m < 2; ++m) {
        #pragma unroll
        for (int n = 0; n < 2; ++n) {
            #pragma unroll
            for (int r = 0; r < 4; ++r) {
                int row = bm0 + wr*32 + m*16 + lg*4 + r;
                int col = bn0 + wc*32 + n*16 + lr;
                if (EPI == 3) {
                    atomicAdd((float*)Cout + (size_t)row*N + col, acc[m][n][r]);
                } else {
                    float v = acc[m][n][r] + (BIAS_ROW ? bias[row] : bias[col]);
                    if (EPI == 2) v = 0.5f * v * (1.0f + erff(v * 0.70710678f));
                    if (OUTBF) ((short*)Cout)[(size_t)row*N + col] = f2bf(v);
                    else       ((float*)Cout)[(size_t)row*N + col] = v;
                }
            }
        }
    }
}

// ---------------- MFMA flash attention: 2 waves, 32-row Q tile, dbuf K/V -------
// qk: [2048 tok][1024] bf16 (q: h*64+d, k: 512+h*64+d);  vt: [512 vd][2048 tok]
__global__ __launch_bounds__(128) void attn_mfma(
    const short* __restrict__ qk, const short* __restrict__ vt,
    const float* __restrict__ coords, const unsigned char* __restrict__ mask,
    const float* __restrict__ w_edge, short* __restrict__ o)
{
    // 1-D grid 512 with XCD swizzle; decompose to (qt, h, b)
    int swz = (blockIdx.x & 7)*64 + (blockIdx.x >> 3);
    int qt = swz & 31, h = (swz >> 5) & 7, b = swz >> 8;
    int tid = threadIdx.x, w = tid >> 6, lane = tid & 63, lr = lane & 15, lg = lane >> 4;

    __shared__ sh8 Ks8[2][512];    // [64 k][64 d] swizzled
    __shared__ sh8 Vts8[2][512];   // [64 d][64 k] swizzled
    __shared__ sh8 Ps8[2][128];    // per-wave P tile [16 q][64 k] swizzled
    __shared__ __attribute__((aligned(16))) unsigned char Msk[2][2048]; // [32 q][64 k]

    // Q fragments in registers (A operand: row = lr, d = s*32 + lg*8..+7)
    int qrow_g = b*NTOK + qt*32 + w*16 + lr;
    sh8 qf[2];
    #pragma unroll
    for (int s = 0; s < 2; ++s)
        qf[s] = *reinterpret_cast<const sh8*>(qk + (size_t)qrow_g*1024 + h*64 + s*32 + lg*8);

    float qx[4], qy[4];
    #pragma unroll
    for (int r = 0; r < 4; ++r) {
        int qr = b*NTOK + qt*32 + w*16 + lg*4 + r;
        float2 c = *reinterpret_cast<const float2*>(&coords[(size_t)qr*2]);
        qx[r] = c.x; qy[r] = c.y;
    }
    float we2 = w_edge[2*NHEADS + h];

    float m_i[4], l_i[4];
    f32x4 zero = {0.f,0.f,0.f,0.f};
    f32x4 accO[4];
    #pragma unroll
    for (int r = 0; r < 4; ++r) { m_i[r] = -1e30f; l_i[r] = 0.f; }
    #pragma unroll
    for (int n = 0; n < 4; ++n) accO[n] = zero;

    #define ASTAGE(buf, jt) { \
        _Pragma("unroll") \
        for (int it = 0; it < 4; ++it) { \
            int s = tid + it*128; \
            int r = s >> 3, g = s & 7; \
            aload16(&Ks8[buf][s],  qk + (size_t)(b*NTOK + (jt)*64 + r)*1024 + 512 + h*64 + ((g ^ (r&7)) << 3)); \
            aload16(&Vts8[buf][s], vt + (size_t)(h*64 + r)*2048 + b*NTOK + (jt)*64 + ((g ^ (r&7)) << 3)); \
        } \
        aload16(&Msk[buf][tid*16], mask + (size_t)(b*NTOK + qt*32 + (tid>>2))*NTOK + (jt)*64 + ((tid&3) << 4)); }

    ASTAGE(0, 0)
    asm volatile("s_waitcnt vmcnt(0)" ::: "memory");
    __syncthreads();

    for (int jt = 0; jt < NTOK/64; ++jt) {
        int buf = jt & 1;
        if (jt + 1 < NTOK/64) ASTAGE(buf ^ 1, jt + 1)

        // S = Q K^T
        f32x4 Sv[4];
        #pragma unroll
        for (int n = 0; n < 4; ++n) {
            f32x4 c = zero;
            int kcol = n*16 + lr;
            #pragma unroll
            for (int s = 0; s < 2; ++s)
                c = mfma16(qf[s], Ks8[buf][kcol*8 + ((s*4+lg) ^ (kcol & 7))], c);
            Sv[n] = c;
        }

        // scale + radial bias + mask
        #pragma unroll
        for (int n = 0; n < 4; ++n) {
            int kcg = b*NTOK + jt*64 + n*16 + lr;
            float2 kc = *reinterpret_cast<const float2*>(&coords[(size_t)kcg*2]);
            #pragma unroll
            for (int r = 0; r < 4; ++r) {
                float dx = qx[r] - kc.x, dy = qy[r] - kc.y;
                float rn = sqrtf(dx*dx + dy*dy);
                float sv = Sv[n][r]*0.125f + rn*we2;
                unsigned char mb = Msk[buf][(w*16 + lg*4 + r)*64 + n*16 + lr];
                Sv[n][r] = mb ? -1e9f : sv;
            }
        }

        // online softmax (row groups of 16 lanes)
        #pragma unroll
        for (int r = 0; r < 4; ++r) {
            float mx = fmaxf(fmaxf(Sv[0][r], Sv[1][r]), fmaxf(Sv[2][r], Sv[3][r]));
            #pragma unroll
            for (int msk = 1; msk < 16; msk <<= 1) mx = fmaxf(mx, __shfl_xor(mx, msk));
            float mnew = fmaxf(m_i[r], mx);
            float f = __expf(m_i[r] - mnew);
            m_i[r] = mnew;
            float rs = 0.f;
            #pragma unroll
            for (int n = 0; n < 4; ++n) { float p = __expf(Sv[n][r] - mnew); Sv[n][r] = p; rs += p; }
            #pragma unroll
            for (int msk = 1; msk < 16; msk <<= 1) rs += __shfl_xor(rs, msk);
            l_i[r] = l_i[r]*f + rs;
            #pragma unroll
            for (int n = 0; n < 4; ++n) accO[n][r] *= f;
        }

        // P -> wave-private LDS (bf16, swizzled)
        short* Pw = (short*)&Ps8[w][0];
        #pragma unroll
        for (int r = 0; r < 4; ++r) {
            int q = lg*4 + r;
            #pragma unroll
            for (int n = 0; n < 4; ++n) {
                int k = n*16 + lr;
                Pw[q*64 + (((k>>3) ^ (q&7)) << 3) + (k&7)] = f2bf(Sv[n][r]);
            }
        }

        // PV
        sh8 pa[2];
        #pragma unroll
        for (int s = 0; s < 2; ++s)
            pa[s] = Ps8[w][lr*8 + ((s*4 + lg) ^ (lr & 7))];
        #pragma unroll
        for (int n = 0; n < 4; ++n) {
            int dcol = n*16 + lr;
            #pragma unroll
            for (int s = 0; s < 2; ++s)
                accO[n] = mfma16(pa[s], Vts8[buf][dcol*8 + ((s*4+lg) ^ (dcol & 7))], accO[n]);
        }

        asm volatile("s_waitcnt vmcnt(0)" ::: "memory");
        __syncthreads();
    }
    #undef ASTAGE

    #pragma unroll
    for (int r = 0; r < 4; ++r) {
        float inv = 1.0f / l_i[r];
        size_t qg = (size_t)(b*NTOK + qt*32 + w*16 + lg*4 + r);
        #pragma unroll
        for (int n = 0; n < 4; ++n)
            o[qg*512 + h*64 + n*16 + lr] = f2bf(accO[n][r] * inv);
    }
}

// -------------------------------------------------------------------------------
extern "C" void kernel_launch(void* const* d_in, const int* in_sizes, int n_in,
                              void* d_out, int out_size, void* d_ws, size_t ws_size,
                              hipStream_t stream)
{
    const float* x      = (const float*)d_in[0];
    const float* coords = (const float*)d_in[1];
    const unsigned char* mask = (const unsigned char*)d_in[2];
    const float* ln1_g = (const float*)d_in[3];
    const float* ln1_b = (const float*)d_in[4];
    const float* w_qkv = (const float*)d_in[5];
    const float* b_qkv = (const float*)d_in[6];
    const float* w_edge= (const float*)d_in[7];
    const float* w_out = (const float*)d_in[8];
    const float* b_out = (const float*)d_in[9];
    const float* ln2_g = (const float*)d_in[10];
    const float* ln2_b = (const float*)d_in[11];
    const float* w1    = (const float*)d_in[12];
    const float* b1    = (const float*)d_in[13];
    const float* w2    = (const float*)d_in[14];
    const float* b2    = (const float*)d_in[15];
    float* out = (float*)d_out;

    char* W = (char*)d_ws;
    const size_t MB = 1024*1024;
    float* x1     = (float*)(W + 0);                 // [0,4M) f32 2048x512
    short* xln    = (short*)(W + 4*MB);              // [4M,6M) bf16 (later: y)
    short* wqkvT  = (short*)(W + 6*MB);              // [6M,7.5M)
    short* woutT  = (short*)(W + 7*MB + 512*1024);   // [7.5M,8M)
    short* qk     = (short*)(W + 8*MB);              // [8M,12M)
    short* vtb    = (short*)(W + 12*MB);             // [12M,14M)
    short* ob     = (short*)(W + 14*MB);             // [14M,16M)
    short* y      = xln;                             // [4M,6M)
    short* w1T    = (short*)(W + 6*MB);              // [6M,8M)  (wqkvT/woutT dead)
    short* w2T    = (short*)(W + 8*MB);              // [8M,10M) (qk dead)
    short* hid    = (short*)(W + 10*MB);             // [10M,18M)

    // ---- phase 1 ----
    wconv_t<<<dim3(1536/32, 512/32), 256, 0, stream>>>(w_qkv, wqkvT, 512, 1536);
    wconv_t<<<dim3(512/32, 512/32), 256, 0, stream>>>(w_out, woutT, 512, 512);
    ln_bf16<<<MTOK, 256, 0, stream>>>(x, ln1_g, ln1_b, xln);
    // qk = xln @ w_qkv[:, :1024]          (512 blocks)
    gemm64<0,true,false,1><<<dim3(512,1,1), 256, 0, stream>>>(
        xln, wqkvT, b_qkv, qk, MTOK, 1024, 512, 16);
    // vt = Wv^T @ xln^T                   (256 blocks)
    gemm64<0,true,true,1><<<dim3(256,1,1), 256, 0, stream>>>(
        wqkvT + (size_t)1024*512, xln, b_qkv + 1024, vtb, 512, MTOK, 512, 32);
    attn_mfma<<<dim3(512,1,1), 128, 0, stream>>>(qk, vtb, coords, mask, w_edge, ob);
    // x1 = (x + b_out) + ob @ w_out       (split-K=2 atomic, 512 blocks)
    addbias_f32<<<1024, 256, 0, stream>>>(x, b_out, x1);
    gemm64<3,false,false,2><<<dim3(256,1,2), 256, 0, stream>>>(
        ob, woutT, nullptr, x1, MTOK, 512, 512, 8);
    // ---- phase 2 ----
    wconv_t<<<dim3(2048/32, 512/32), 256, 0, stream>>>(w1, w1T, 512, 2048);
    wconv_t<<<dim3(512/32, 2048/32), 256, 0, stream>>>(w2, w2T, 2048, 512);
    ln_bf16<<<MTOK, 256, 0, stream>>>(x1, ln2_g, ln2_b, y);
    // hid = gelu(y @ w1 + b1)             (1024 blocks)
    gemm64<2,true,false,1><<<dim3(1024,1,1), 256, 0, stream>>>(
        y, w1T, b1, hid, MTOK, 2048, 512, 32);
    // out = (x1 + b2) + hid @ w2          (split-K=4 atomic, 1024 blocks)
    addbias_f32<<<1024, 256, 0, stream>>>(x1, b2, out);
    gemm64<3,false,false,4><<<dim3(256,1,4), 256, 0, stream>>>(
        hid, w2T, nullptr, out, MTOK, 512, 2048, 8);
}

// Round 4
// 125.692 us; speedup vs baseline: 1.1632x; 1.1632x over previous
//
#include <hip/hip_runtime.h>
#include <hip/hip_bf16.h>
#include <math.h>

#define NHEADS 8
#define NTOK   1024
#define MTOK   2048

typedef __attribute__((ext_vector_type(8))) short  sh8;
typedef __attribute__((ext_vector_type(8))) __bf16 bf16x8;
typedef __attribute__((ext_vector_type(4))) float  f32x4;

__device__ __forceinline__ short f2bf(float v) {
    return __builtin_bit_cast(short, __float2bfloat16(v));
}
__device__ __forceinline__ f32x4 mfma16(sh8 a, sh8 b, f32x4 c) {
    return __builtin_amdgcn_mfma_f32_16x16x32_bf16(
        __builtin_bit_cast(bf16x8, a), __builtin_bit_cast(bf16x8, b), c, 0, 0, 0);
}
__device__ __forceinline__ void aload16(void* lds, const void* g) {
    __builtin_amdgcn_global_load_lds(
        (const __attribute__((address_space(1))) unsigned int*)g,
        (__attribute__((address_space(3))) unsigned int*)lds, 16, 0, 0);
}

// ---------------- LayerNorm -> bf16 ----------------
__global__ __launch_bounds__(256) void ln_bf16(const float* __restrict__ x,
    const float* __restrict__ g, const float* __restrict__ bta, short* __restrict__ y)
{
    int row = blockIdx.x, t = threadIdx.x;
    const float* xr = x + (size_t)row * 512;
    float2 v = *reinterpret_cast<const float2*>(&xr[t*2]);
    float s = v.x + v.y, ss = v.x*v.x + v.y*v.y;
    #pragma unroll
    for (int m = 1; m < 64; m <<= 1) { s += __shfl_xor(s, m); ss += __shfl_xor(ss, m); }
    __shared__ float red[8];
    int wid = t >> 6, lane = t & 63;
    if (!lane) { red[wid] = s; red[4+wid] = ss; }
    __syncthreads();
    s = red[0]+red[1]+red[2]+red[3]; ss = red[4]+red[5]+red[6]+red[7];
    float mu = s*(1.f/512), var = ss*(1.f/512) - mu*mu, rs = rsqrtf(var + 1e-5f);
    float2 gg = *reinterpret_cast<const float2*>(&g[t*2]);
    float2 bb = *reinterpret_cast<const float2*>(&bta[t*2]);
    short2 o; o.x = f2bf((v.x-mu)*rs*gg.x + bb.x); o.y = f2bf((v.y-mu)*rs*gg.y + bb.y);
    *reinterpret_cast<short2*>(&y[(size_t)row*512 + t*2]) = o;
}

// ---------------- fp32 W[K][N] -> bf16 W^T[N][K] ----------------
__global__ __launch_bounds__(256) void wconv_t(const float* __restrict__ W,
    short* __restrict__ WT, int K, int N)
{
    __shared__ float t[32][33];
    int bn = blockIdx.x * 32, bk = blockIdx.y * 32;
    int c = threadIdx.x & 31, r8 = threadIdx.x >> 5;
    #pragma unroll
    for (int i = 0; i < 4; ++i) {
        int r = r8 + i*8;
        t[r][c] = W[(size_t)(bk + r)*N + bn + c];
    }
    __syncthreads();
    #pragma unroll
    for (int i = 0; i < 4; ++i) {
        int r = r8 + i*8;
        WT[(size_t)(bn + r)*K + bk + c] = f2bf(t[c][r]);
    }
}

// ---------------- o[i] = a[i] + bias[i % 512]  (f32, vectorized) ----------------
__global__ __launch_bounds__(256) void addbias_f32(const float* __restrict__ a,
    const float* __restrict__ bias, float* __restrict__ o)
{
    int e = (blockIdx.x*256 + threadIdx.x)*4;
    float4 av = *reinterpret_cast<const float4*>(a + e);
    float4 bv = *reinterpret_cast<const float4*>(bias + (e & 511));
    float4 ov = {av.x+bv.x, av.y+bv.y, av.z+bv.z, av.w+bv.w};
    *reinterpret_cast<float4*>(o + e) = ov;
}

// ---------------- bf16 MFMA GEMM, 64x64 tile, BK=64, 2-phase dbuf --------------
template<int EPI, bool OUTBF, bool BIAS_ROW, int SPLITK>
__global__ __launch_bounds__(256) void gemm64(
    const short* __restrict__ A, const short* __restrict__ BT,
    const float* __restrict__ bias, void* __restrict__ Cout,
    int M, int N, int K, int nbx)
{
    __shared__ sh8 As8[2][512];
    __shared__ sh8 Bs8[2][512];
    int tid = threadIdx.x;
    int w = tid >> 6, lane = tid & 63, lr = lane & 15, lg = lane >> 4;
    int wr = w >> 1, wc = w & 1;
    int cpx = gridDim.x >> 3;
    int swz = (blockIdx.x & 7)*cpx + (blockIdx.x >> 3);
    int bx = swz % nbx, by = swz / nbx;
    int bm0 = by*64, bn0 = bx*64;
    int kbeg = (K / SPLITK) * blockIdx.z;
    int nt = (K / SPLITK) / 64;

    f32x4 zero = {0.f,0.f,0.f,0.f};
    f32x4 acc[2][2];
    #pragma unroll
    for (int m = 0; m < 2; ++m)
        #pragma unroll
        for (int n = 0; n < 2; ++n) acc[m][n] = zero;

    #define STAGE(buf, k0) { \
        _Pragma("unroll") \
        for (int it = 0; it < 2; ++it) { \
            int s = tid + it*256; \
            int r = s >> 3, g = s & 7; \
            int ksw = (k0) + ((g ^ (r & 7)) << 3); \
            aload16(&As8[buf][s], A  + (size_t)(bm0 + r)*K + ksw); \
            aload16(&Bs8[buf][s], BT + (size_t)(bn0 + r)*K + ksw); \
        } }

    STAGE(0, kbeg)
    asm volatile("s_waitcnt vmcnt(0)" ::: "memory");
    __syncthreads();

    for (int t = 0; t < nt; ++t) {
        int buf = t & 1;
        if (t + 1 < nt) STAGE(buf ^ 1, kbeg + (t+1)*64)
        sh8 af[2][2], bfv[2][2];
        #pragma unroll
        for (int m = 0; m < 2; ++m) {
            int R = wr*32 + m*16 + lr;
            #pragma unroll
            for (int s = 0; s < 2; ++s) af[m][s] = As8[buf][R*8 + ((s*4+lg) ^ (R & 7))];
        }
        #pragma unroll
        for (int n = 0; n < 2; ++n) {
            int R = wc*32 + n*16 + lr;
            #pragma unroll
            for (int s = 0; s < 2; ++s) bfv[n][s] = Bs8[buf][R*8 + ((s*4+lg) ^ (R & 7))];
        }
        #pragma unroll
        for (int m = 0; m < 2; ++m)
            #pragma unroll
            for (int n = 0; n < 2; ++n)
                #pragma unroll
                for (int s = 0; s < 2; ++s)
                    acc[m][n] = mfma16(af[m][s], bfv[n][s], acc[m][n]);
        asm volatile("s_waitcnt vmcnt(0)" ::: "memory");
        __syncthreads();
    }
    #undef STAGE

    #pragma unroll
    for (int m = 0; m < 2; ++m) {
        #pragma unroll
        for (int n = 0; n < 2; ++n) {
            #pragma unroll
            for (int r = 0; r < 4; ++r) {
                int row = bm0 + wr*32 + m*16 + lg*4 + r;
                int col = bn0 + wc*32 + n*16 + lr;
                if (EPI == 3) {
                    atomicAdd((float*)Cout + (size_t)row*N + col, acc[m][n][r]);
                } else {
                    float v = acc[m][n][r] + (BIAS_ROW ? bias[row] : bias[col]);
                    if (EPI == 2) v = 0.5f * v * (1.0f + erff(v * 0.70710678f));
                    if (OUTBF) ((short*)Cout)[(size_t)row*N + col] = f2bf(v);
                    else       ((float*)Cout)[(size_t)row*N + col] = v;
                }
            }
        }
    }
}

// ---------------- barrier-free register-KV flash attention, KV-split x2 -------
// qk: [2048 tok][1024] bf16 (q: h*64+d, k: 512+h*64+d);  vt: [512 vd][2048 tok]
// Each wave: 16 q rows, 8 KV tiles. Partials (unnormalized O, m, l) -> ws.
__global__ __launch_bounds__(256) void attn_reg(
    const short* __restrict__ qk, const short* __restrict__ vt,
    const float* __restrict__ coords, const unsigned char* __restrict__ mask,
    const float* __restrict__ w_edge, float* __restrict__ Op, float* __restrict__ ml)
{
    __shared__ sh8 Ps8[4][128];   // per-wave P tile [16 q][64 k], swizzled

    int swz = (blockIdx.x & 7)*64 + (blockIdx.x >> 3);   // 512 blocks, bijective
    int w = threadIdx.x >> 6, lane = threadIdx.x & 63;
    int lr = lane & 15, lg = lane >> 4;
    int gw = swz*4 + w;
    int qt = gw & 63;          // q tile of 16 rows
    int h  = (gw >> 6) & 7;
    int b  = (gw >> 9) & 1;
    int ks = gw >> 10;         // KV split 0/1

    const int qrow0 = b*NTOK + qt*16;

    // Q fragments (A operand: row = lr, d = s*32 + lg*8..+7)
    sh8 qf[2];
    #pragma unroll
    for (int s = 0; s < 2; ++s)
        qf[s] = *reinterpret_cast<const sh8*>(qk + (size_t)(qrow0 + lr)*1024 + h*64 + s*32 + lg*8);

    float qx[4], qy[4];
    #pragma unroll
    for (int r = 0; r < 4; ++r) {
        float2 c = *reinterpret_cast<const float2*>(&coords[(size_t)(qrow0 + lg*4 + r)*2]);
        qx[r] = c.x; qy[r] = c.y;
    }
    float we2 = w_edge[2*NHEADS + h];

    float m_i[4], l_i[4];
    f32x4 zero = {0.f,0.f,0.f,0.f};
    f32x4 accO[4];
    #pragma unroll
    for (int r = 0; r < 4; ++r) { m_i[r] = -1e30f; l_i[r] = 0.f; }
    #pragma unroll
    for (int n = 0; n < 4; ++n) accO[n] = zero;

    const short* kb = qk + 512 + h*64;                 // + tok*1024 + s*32 + lg*8
    const short* vb = vt + (size_t)h*64*2048 + b*NTOK; // + d*2048 + tok

    for (int t = 0; t < 8; ++t) {
        int jt = ks*8 + t;
        int k0 = b*NTOK + jt*64;

        // K fragments (B operand: col k = n*16+lr, d slices by lg)
        sh8 kf0[4], kf1[4];
        #pragma unroll
        for (int n = 0; n < 4; ++n) {
            const short* kr = kb + (size_t)(k0 + n*16 + lr)*1024 + lg*8;
            kf0[n] = *reinterpret_cast<const sh8*>(kr);
            kf1[n] = *reinterpret_cast<const sh8*>(kr + 32);
        }
        // V fragments issued early too (B operand for PV: col d = n*16+lr, k slices)
        sh8 vf0[4], vf1[4];
        #pragma unroll
        for (int n = 0; n < 4; ++n) {
            const short* vr = vb + (size_t)(h*0 + n*16 + lr)*2048 + jt*64 + lg*8;
            vf0[n] = *reinterpret_cast<const sh8*>(vr);
            vf1[n] = *reinterpret_cast<const sh8*>(vr + 32);
        }
        // mask + k coords
        float2 kc[4];
        unsigned char mb[4][4];
        #pragma unroll
        for (int n = 0; n < 4; ++n)
            kc[n] = *reinterpret_cast<const float2*>(&coords[(size_t)(k0 + n*16 + lr)*2]);
        #pragma unroll
        for (int r = 0; r < 4; ++r)
            #pragma unroll
            for (int n = 0; n < 4; ++n)
                mb[r][n] = mask[(size_t)(qrow0 + lg*4 + r)*NTOK + jt*64 + n*16 + lr];

        // S = Q K^T
        f32x4 Sv[4];
        #pragma unroll
        for (int n = 0; n < 4; ++n)
            Sv[n] = mfma16(qf[1], kf1[n], mfma16(qf[0], kf0[n], zero));

        // scale + radial bias + mask
        #pragma unroll
        for (int n = 0; n < 4; ++n) {
            #pragma unroll
            for (int r = 0; r < 4; ++r) {
                float dx = qx[r] - kc[n].x, dy = qy[r] - kc[n].y;
                float rn = sqrtf(dx*dx + dy*dy);
                float sv = Sv[n][r]*0.125f + rn*we2;
                Sv[n][r] = mb[r][n] ? -1e9f : sv;
            }
        }

        // online softmax (row = 16 lanes sharing lg)
        #pragma unroll
        for (int r = 0; r < 4; ++r) {
            float mx = fmaxf(fmaxf(Sv[0][r], Sv[1][r]), fmaxf(Sv[2][r], Sv[3][r]));
            #pragma unroll
            for (int msk = 1; msk < 16; msk <<= 1) mx = fmaxf(mx, __shfl_xor(mx, msk));
            float mnew = fmaxf(m_i[r], mx);
            float f = __expf(m_i[r] - mnew);
            m_i[r] = mnew;
            float rs = 0.f;
            #pragma unroll
            for (int n = 0; n < 4; ++n) { float p = __expf(Sv[n][r] - mnew); Sv[n][r] = p; rs += p; }
            #pragma unroll
            for (int msk = 1; msk < 16; msk <<= 1) rs += __shfl_xor(rs, msk);
            l_i[r] = l_i[r]*f + rs;
            #pragma unroll
            for (int n = 0; n < 4; ++n) accO[n][r] *= f;
        }

        // P -> wave-private LDS (swizzled), reload as A fragments
        short* Pw = (short*)&Ps8[w][0];
        #pragma unroll
        for (int r = 0; r < 4; ++r) {
            int q = lg*4 + r;
            #pragma unroll
            for (int n = 0; n < 4; ++n) {
                int k = n*16 + lr;
                Pw[q*64 + (((k>>3) ^ (q&7)) << 3) + (k&7)] = f2bf(Sv[n][r]);
            }
        }
        sh8 pa[2];
        #pragma unroll
        for (int s = 0; s < 2; ++s)
            pa[s] = Ps8[w][lr*8 + ((s*4 + lg) ^ (lr & 7))];

        // PV
        #pragma unroll
        for (int n = 0; n < 4; ++n)
            accO[n] = mfma16(pa[1], vf1[n], mfma16(pa[0], vf0[n], accO[n]));
    }

    // partials: unnormalized O + (m, l)
    #pragma unroll
    for (int r = 0; r < 4; ++r) {
        size_t row = (size_t)(ks*MTOK + qrow0 + lg*4 + r);
        #pragma unroll
        for (int n = 0; n < 4; ++n)
            Op[row*512 + h*64 + n*16 + lr] = accO[n][r];
        if (lr == 0) {
            ml[(row*NHEADS + h)*2 + 0] = m_i[r];
            ml[(row*NHEADS + h)*2 + 1] = l_i[r];
        }
    }
}

// ---------------- combine KV-split partials -> bf16 O ----------------
__global__ __launch_bounds__(256) void attn_combine(const float* __restrict__ Op,
    const float* __restrict__ ml, short* __restrict__ ob)
{
    int idx = blockIdx.x*256 + threadIdx.x;     // MTOK*128 threads
    int tok = idx >> 7, dd = (idx & 127) * 4;
    int h = dd >> 6;
    float m0 = ml[((size_t)tok*NHEADS + h)*2 + 0];
    float l0 = ml[((size_t)tok*NHEADS + h)*2 + 1];
    float m1 = ml[(((size_t)MTOK + tok)*NHEADS + h)*2 + 0];
    float l1 = ml[(((size_t)MTOK + tok)*NHEADS + h)*2 + 1];
    float mm = fmaxf(m0, m1);
    float w0 = __expf(m0 - mm), w1 = __expf(m1 - mm);
    float inv = 1.f / (w0*l0 + w1*l1);
    float4 a = *reinterpret_cast<const float4*>(&Op[(size_t)tok*512 + dd]);
    float4 c = *reinterpret_cast<const float4*>(&Op[((size_t)MTOK + tok)*512 + dd]);
    short4 o;
    o.x = f2bf((a.x*w0 + c.x*w1)*inv);
    o.y = f2bf((a.y*w0 + c.y*w1)*inv);
    o.z = f2bf((a.z*w0 + c.z*w1)*inv);
    o.w = f2bf((a.w*w0 + c.w*w1)*inv);
    *reinterpret_cast<short4*>(&ob[(size_t)tok*512 + dd]) = o;
}

// -------------------------------------------------------------------------------
extern "C" void kernel_launch(void* const* d_in, const int* in_sizes, int n_in,
                              void* d_out, int out_size, void* d_ws, size_t ws_size,
                              hipStream_t stream)
{
    const float* x      = (const float*)d_in[0];
    const float* coords = (const float*)d_in[1];
    const unsigned char* mask = (const unsigned char*)d_in[2];
    const float* ln1_g = (const float*)d_in[3];
    const float* ln1_b = (const float*)d_in[4];
    const float* w_qkv = (const float*)d_in[5];
    const float* b_qkv = (const float*)d_in[6];
    const float* w_edge= (const float*)d_in[7];
    const float* w_out = (const float*)d_in[8];
    const float* b_out = (const float*)d_in[9];
    const float* ln2_g = (const float*)d_in[10];
    const float* ln2_b = (const float*)d_in[11];
    const float* w1    = (const float*)d_in[12];
    const float* b1    = (const float*)d_in[13];
    const float* w2    = (const float*)d_in[14];
    const float* b2    = (const float*)d_in[15];
    float* out = (float*)d_out;

    char* W = (char*)d_ws;
    const size_t MB = 1024*1024;
    // liveness-planned layout (max 22.75 MB)
    float* x1    = (float*)(W);                   // [0,4M) f32, post-combine
    short* qk    = (short*)(W + 4*MB);            // [4M,8M)   (later w1T/w2T)
    short* vtb   = (short*)(W + 8*MB);            // [8M,10M)
    short* woutT = (short*)(W + 10*MB);           // [10M,10.5M)
    short* xln   = (short*)(W + 10*MB + 512*1024);// [10.5M,12.5M)  (later y)
    short* wqkvT = (short*)(W + 12*MB + 512*1024);// [12.5M,14M)    (later ob)
    short* ob    = (short*)(W + 12*MB + 512*1024);// [12.5M,14.5M)
    float* Opart = (float*)(W + 14*MB + 512*1024);// [14.5M,22.5M)  (later hid)
    float* mlp   = (float*)(W + 22*MB + 512*1024);// [22.5M,22.75M)
    short* y     = xln;
    short* w1T   = (short*)(W + 4*MB);            // [4M,6M)
    short* w2T   = (short*)(W + 6*MB);            // [6M,8M)
    short* hid   = (short*)(W + 14*MB + 512*1024);// [14.5M,22.5M)

    // ---- phase 1 ----
    wconv_t<<<dim3(1536/32, 512/32), 256, 0, stream>>>(w_qkv, wqkvT, 512, 1536);
    wconv_t<<<dim3(512/32, 512/32), 256, 0, stream>>>(w_out, woutT, 512, 512);
    ln_bf16<<<MTOK, 256, 0, stream>>>(x, ln1_g, ln1_b, xln);
    gemm64<0,true,false,1><<<dim3(512,1,1), 256, 0, stream>>>(
        xln, wqkvT, b_qkv, qk, MTOK, 1024, 512, 16);
    gemm64<0,true,true,1><<<dim3(256,1,1), 256, 0, stream>>>(
        wqkvT + (size_t)1024*512, xln, b_qkv + 1024, vtb, 512, MTOK, 512, 32);
    attn_reg<<<dim3(512,1,1), 256, 0, stream>>>(qk, vtb, coords, mask, w_edge, Opart, mlp);
    attn_combine<<<dim3(1024,1,1), 256, 0, stream>>>(Opart, mlp, ob);
    addbias_f32<<<1024, 256, 0, stream>>>(x, b_out, x1);
    gemm64<3,false,false,2><<<dim3(256,1,2), 256, 0, stream>>>(
        ob, woutT, nullptr, x1, MTOK, 512, 512, 8);
    // ---- phase 2 ----
    wconv_t<<<dim3(2048/32, 512/32), 256, 0, stream>>>(w1, w1T, 512, 2048);
    wconv_t<<<dim3(512/32, 2048/32), 256, 0, stream>>>(w2, w2T, 2048, 512);
    ln_bf16<<<MTOK, 256, 0, stream>>>(x1, ln2_g, ln2_b, y);
    gemm64<2,true,false,1><<<dim3(1024,1,1), 256, 0, stream>>>(
        y, w1T, b1, hid, MTOK, 2048, 512, 32);
    addbias_f32<<<1024, 256, 0, stream>>>(x1, b2, out);
    gemm64<3,false,false,4><<<dim3(256,1,4), 256, 0, stream>>>(
        hid, w2T, nullptr, out, MTOK, 512, 2048, 8);
}